// Round 7
// baseline (45332.877 us; speedup 1.0000x reference)
//
#include <hip/hip_runtime.h>

// ============================================================================
// Bidirectional LSTM with projection — persistent kernel, rev 4 (plain launch).
//   B=64, S=1024, E=256, H=1024, P=256 ; out (B,S,2*256) fp32
// 8 teams (2 dir x 4 batch-groups of 16), 32 WGs/team, grid 256 x 256 thr.
// Co-residency: >256 VGPRs/wave forces 1 WG/CU; 256 WGs == 256 CUs.
// ALL weights VGPR-resident as MFMA B-fragments (hi+lo bf16 split, 3-pass
// MFMA => fp32-class accuracy). LDS: 22.5KB static for gate/proj reduce.
// rev 4: flag-array team barriers (one 128B-padded slot per WG, store-release
// epoch; waiters poll 32 slots in parallel + ballot) replace the 32-way
// serialized atomic counter. Global abort flag bounds worst-case spin (~15ms).
// Resubmitted unchanged after desk-audit (round 6: broker never ran it).
// ============================================================================

#define NS 1024
#define NE 256
#define NH 1024
#define NP 256
#define MB 16
#define NTH 256
#define TEAMS 8
#define TWGS 32

typedef __attribute__((ext_vector_type(8))) short bf16x8;
typedef __attribute__((ext_vector_type(4))) float f32x4;
typedef __attribute__((ext_vector_type(2))) float f32x2;

// ---- ws layout (bytes) ----
// flags: per team 8KB = [act: 32 slots x 128B][h: 32 slots x 128B]
#define WS_FLAGS  0
#define WS_ABORT  65536                    // unsigned abort flag
#define WS_HHI    65792                    // u16 [8][16][256]
#define WS_HLO    (WS_HHI + 65536)
#define WS_ACTHI  (WS_HLO + 65536)         // u16 [8][16][1024]
#define WS_ACTLO  (WS_ACTHI + 262144)
#define WS_END    (WS_ACTLO + 262144)
#define WS_ZERO   WS_ACTHI                 // flags+abort+h must start at 0

__device__ __forceinline__ unsigned short f2bf_rne(float f){
  unsigned u = __builtin_bit_cast(unsigned, f);
  u += 0x7fffu + ((u >> 16) & 1u);
  return (unsigned short)(u >> 16);
}
__device__ __forceinline__ unsigned short f2bf_tr(float f){
  return (unsigned short)(__builtin_bit_cast(unsigned, f) >> 16);
}
__device__ __forceinline__ float bf2f(unsigned short h){
  unsigned u = ((unsigned)h) << 16;
  return __builtin_bit_cast(float, u);
}
__device__ __forceinline__ f32x4 MFMA(bf16x8 a, bf16x8 b, f32x4 c){
  return __builtin_amdgcn_mfma_f32_16x16x32_bf16(a, b, c, 0, 0, 0);
}
__device__ __forceinline__ float sigmf(float x){ return 1.0f / (1.0f + __expf(-x)); }
__device__ __forceinline__ float tanhfast(float x){
  x = fminf(fmaxf(x, -15.0f), 15.0f);
  float t = __expf(2.0f * x);
  return (t - 1.0f) / (t + 1.0f);
}
__device__ __forceinline__ void fence_rel(){ __builtin_amdgcn_fence(__ATOMIC_RELEASE, "agent"); }
__device__ __forceinline__ void fence_acq(){ __builtin_amdgcn_fence(__ATOMIC_ACQUIRE, "agent"); }

// Wait until all 32 team flags reach tgt. Lane l polls slot (l&31); full-wave
// ballot detects completion. tgt==0 is the s==0 bootstrap (flags memset 0).
__device__ __forceinline__ void wait_flags(const unsigned* flags, unsigned tgt,
                                           unsigned* abortf){
  if (tgt == 0u) return;
  const unsigned* myp = flags + (threadIdx.x & 31) * 32;   // 128B stride
  unsigned it = 0;
  for(;;){
    unsigned v = __hip_atomic_load(myp, __ATOMIC_RELAXED, __HIP_MEMORY_SCOPE_AGENT);
    if (__ballot(v >= tgt) == ~0ULL) break;
    if ((++it & 63u) == 0u){
      if (__hip_atomic_load(abortf, __ATOMIC_RELAXED, __HIP_MEMORY_SCOPE_AGENT) != 0u) return;
      if (it > 100000u){  // ~15ms: declare deadlock, abort everyone, fail loud
        __hip_atomic_store(abortf, 1u, __ATOMIC_RELAXED, __HIP_MEMORY_SCOPE_AGENT);
        return;
      }
    }
  }
}

struct Params {
  const float* x;
  const float* Wih_f; const float* Whh_f; const float* bih_f; const float* bhh_f; const float* Whr_f;
  const float* Wih_b; const float* Whh_b; const float* bih_b; const float* bhh_b; const float* Whr_b;
  float* out;
  unsigned char* ws;
};

__launch_bounds__(NTH, 1)
__global__ void lstm_kernel(Params p){
  // LDS: Gred [4 tilesets][4 gates][16 batch][18] ; G2red [4 waves][16 batch][18]
  __shared__ float Gred[4*4*16*18];    // 18KB
  __shared__ float G2red[4*16*18];     // 4.5KB

  const int tid  = threadIdx.x;
  const int w    = tid >> 6;       // wave 0..3
  const int lane = tid & 63;
  const int rl   = lane & 15;
  const int kgrp = lane >> 4;

  const int bid = blockIdx.x;
  const int tm  = bid & 7;         // team (XCD-affine under %8 round-robin; perf-only)
  const int wg  = bid >> 3;        // 0..31 within team
  const int dir = tm >> 2;
  const int bg  = tm & 3;

  const float* Wih = dir ? p.Wih_b : p.Wih_f;
  const float* Whh = dir ? p.Whh_b : p.Whh_f;
  const float* bih = dir ? p.bih_b : p.bih_f;
  const float* bhh = dir ? p.bhh_b : p.bhh_f;
  const float* Whr = dir ? p.Whr_b : p.Whr_f;

  unsigned* act_flags = (unsigned*)(p.ws + WS_FLAGS + tm*8192);
  unsigned* h_flags   = (unsigned*)(p.ws + WS_FLAGS + tm*8192 + 4096);
  unsigned* my_act_flag = act_flags + wg*32;   // this WG's 128B slot
  unsigned* my_h_flag   = h_flags   + wg*32;
  unsigned* abortf  = (unsigned*)(p.ws + WS_ABORT);
  unsigned short* h_hi   = (unsigned short*)(p.ws + WS_HHI)   + tm*MB*NP;
  unsigned short* h_lo   = (unsigned short*)(p.ws + WS_HLO)   + tm*MB*NP;
  unsigned short* act_hi = (unsigned short*)(p.ws + WS_ACTHI) + tm*MB*NH;
  unsigned short* act_lo = (unsigned short*)(p.ws + WS_ACTLO) + tm*MB*NH;

  // Roles: hb = which 16 of this WG's 32 h-indices; kh = K-half
  //   kh==0 -> A = h(s-1) (W_hh), kh==1 -> A = x[sx] (W_ih)
  const int hb = w & 1;
  const int kh = w >> 1;

  // -------- W1 slice (hi+lo) -> VGPR B-frags: whi/wlo[gate][ktile] ----------
  // B-frag for 16x16x32: lane holds col n=rl (gate-row), k = kt*32+kgrp*8+j
  const float* Wsel = kh ? Wih : Whh;
  bf16x8 whi[4][8], wlo[4][8];
  #pragma unroll
  for (int g = 0; g < 4; ++g){
    const float* Wrow = Wsel + (size_t)(g*NH + wg*32 + hb*16 + rl)*NE;
    #pragma unroll
    for (int kt = 0; kt < 8; ++kt){
      const int k0 = kt*32 + kgrp*8;
      #pragma unroll
      for (int j = 0; j < 8; ++j){
        float v = Wrow[k0 + j];
        unsigned short hv = f2bf_rne(v);
        whi[g][kt][j] = (short)hv;
        wlo[g][kt][j] = (short)f2bf_rne(v - bf2f(hv));
      }
    }
  }

  // -------- W_hr slice (hi+lo) -> VGPR B-frags; wave w owns K chunk --------
  bf16x8 whrh[8], whrl[8];
  #pragma unroll
  for (int q = 0; q < 8; ++q){
    const int k0 = w*256 + q*32 + kgrp*8;
    #pragma unroll
    for (int j = 0; j < 8; ++j){
      float v = (rl < 8) ? Whr[(size_t)(wg*8 + rl)*NH + k0 + j] : 0.0f;
      unsigned short hv = f2bf_rne(v);
      whrh[q][j] = (short)hv;
      whrl[q][j] = (short)f2bf_rne(v - bf2f(hv));
    }
  }

  // -------- bias (added once, kh==0 half only) -----------------------------
  float bias[4];
  #pragma unroll
  for (int g = 0; g < 4; ++g){
    const int grow = g*NH + wg*32 + hb*16 + rl;
    bias[g] = (kh == 0) ? (bih[grow] + bhh[grow]) : 0.0f;
  }

  // -------- gate-phase role: thread owns (hb, batch gb16, h-pair ghidx) ----
  const int bh2   = w >> 1;
  const int idx0  = lane * 2;
  const int gb16  = bh2*8 + (idx0 >> 4);
  const int ghidx = idx0 & 15;
  float c0 = 0.0f, c1 = 0.0f;          // persistent cell state (fp32)

  for (int s = 0; s < NS; ++s){
    const int sx = dir ? (NS-1-s) : s;

    f32x4 acc[4];
    #pragma unroll
    for (int g = 0; g < 4; ++g) acc[g] = (f32x4){bias[g], bias[g], bias[g], bias[g]};

    if (kh == 0){
      // recurrent half: wait for h(s-1) (s==0 passes: flags zeroed)
      wait_flags(h_flags, (unsigned)s, abortf);
      fence_acq();
      #pragma unroll
      for (int kt = 0; kt < 8; ++kt){
        const int k0 = kt*32 + kgrp*8;
        bf16x8 ahi = *(const bf16x8*)(h_hi + rl*NP + k0);
        bf16x8 alo = *(const bf16x8*)(h_lo + rl*NP + k0);
        #pragma unroll
        for (int g = 0; g < 4; ++g){
          acc[g] = MFMA(ahi, whi[g][kt], acc[g]);
          acc[g] = MFMA(alo, whi[g][kt], acc[g]);
          acc[g] = MFMA(ahi, wlo[g][kt], acc[g]);
        }
      }
    } else {
      // input half: no dependence on previous step
      const float* xb = p.x + ((size_t)(bg*16 + rl)*NS + (size_t)sx)*NE;
      #pragma unroll
      for (int kt = 0; kt < 8; ++kt){
        const int k0 = kt*32 + kgrp*8;
        f32x4 va = *(const f32x4*)(xb + k0);
        f32x4 vb = *(const f32x4*)(xb + k0 + 4);
        bf16x8 ahi, alo;
        #pragma unroll
        for (int j = 0; j < 4; ++j){
          unsigned short h1 = f2bf_tr(va[j]);
          ahi[j]   = (short)h1; alo[j]   = (short)f2bf_tr(va[j] - bf2f(h1));
          unsigned short h2 = f2bf_tr(vb[j]);
          ahi[j+4] = (short)h2; alo[j+4] = (short)f2bf_tr(vb[j] - bf2f(h2));
        }
        #pragma unroll
        for (int g = 0; g < 4; ++g){
          acc[g] = MFMA(ahi, whi[g][kt], acc[g]);
          acc[g] = MFMA(alo, whi[g][kt], acc[g]);
          acc[g] = MFMA(ahi, wlo[g][kt], acc[g]);
        }
      }
    }

    // deposit partials: D lane layout row(batch)=kgrp*4+r, col(h)=rl
    #pragma unroll
    for (int g = 0; g < 4; ++g){
      #pragma unroll
      for (int r = 0; r < 4; ++r)
        Gred[(((kh*2+hb)*4 + g)*16 + (kgrp*4 + r))*18 + rl] = acc[g][r];
    }
    __syncthreads();

    // ---- gates + cell update + activation (2 h-elems per thread) ----------
    {
      unsigned short ahi16[2], alo16[2];
      float gs[4][2];
      #pragma unroll
      for (int g = 0; g < 4; ++g){
        f32x2 a0 = *(const f32x2*)&Gred[((hb*4 + g)*16 + gb16)*18 + ghidx];
        f32x2 a1 = *(const f32x2*)&Gred[(((2+hb)*4 + g)*16 + gb16)*18 + ghidx];
        gs[g][0] = a0[0] + a1[0];
        gs[g][1] = a0[1] + a1[1];
      }
      #pragma unroll
      for (int j = 0; j < 2; ++j){
        float iv = sigmf(gs[0][j]);
        float fv = sigmf(gs[1][j]);
        float gv = tanhfast(gs[2][j]);
        float ov = sigmf(gs[3][j]);
        float c  = fv * (j ? c1 : c0) + iv * gv;
        if (j) c1 = c; else c0 = c;
        float a  = ov * tanhfast(c);
        ahi16[j] = f2bf_tr(a);
        alo16[j] = f2bf_tr(a - bf2f(ahi16[j]));
      }
      const unsigned colg = (unsigned)(wg*32 + hb*16 + ghidx);
      *(unsigned*)(act_hi + gb16*NH + colg) = (unsigned)ahi16[0] | ((unsigned)ahi16[1] << 16);
      *(unsigned*)(act_lo + gb16*NH + colg) = (unsigned)alo16[0] | ((unsigned)alo16[1] << 16);
    }
    fence_rel();
    __syncthreads();
    if (tid == 0)
      __hip_atomic_store(my_act_flag, (unsigned)(s+1), __ATOMIC_RELEASE, __HIP_MEMORY_SCOPE_AGENT);
    wait_flags(act_flags, (unsigned)(s+1), abortf);
    fence_acq();

    // ---- GEMM2: h = act @ W_hr.T ; waves split K=1024, LDS reduce ---------
    f32x4 acc2 = (f32x4){0.0f, 0.0f, 0.0f, 0.0f};
    #pragma unroll
    for (int q = 0; q < 8; ++q){
      const int k0 = w*256 + q*32 + kgrp*8;
      bf16x8 ahi = *(const bf16x8*)(act_hi + rl*NH + k0);
      bf16x8 alo = *(const bf16x8*)(act_lo + rl*NH + k0);
      acc2 = MFMA(ahi, whrh[q], acc2);
      acc2 = MFMA(alo, whrh[q], acc2);
      acc2 = MFMA(ahi, whrl[q], acc2);
    }
    #pragma unroll
    for (int r = 0; r < 4; ++r)
      G2red[(w*16 + (kgrp*4 + r))*18 + rl] = acc2[r];
    __syncthreads();

    // ---- projection reduce: h-write + signal FIRST, out-store AFTER -------
    float vout[4];
    if (w == 0){
      #pragma unroll
      for (int r = 0; r < 4; ++r){
        const int b16 = kgrp*4 + r;
        float v = G2red[(0*16 + b16)*18 + rl] + G2red[(1*16 + b16)*18 + rl]
                + G2red[(2*16 + b16)*18 + rl] + G2red[(3*16 + b16)*18 + rl];
        vout[r] = v;
        if (rl < 8){
          const int pcol = wg*8 + rl;
          unsigned short hh = f2bf_tr(v);
          h_hi[b16*NP + pcol] = hh;
          h_lo[b16*NP + pcol] = f2bf_tr(v - bf2f(hh));
        }
      }
      fence_rel();   // wave-level: orders all wave-0 lanes' h stores
      if (lane == 0)
        __hip_atomic_store(my_h_flag, (unsigned)(s+1), __ATOMIC_RELEASE, __HIP_MEMORY_SCOPE_AGENT);

      if (rl < 8){
        // write-only output; retires during the next step's spin window
        const int pcol = wg*8 + rl;
        #pragma unroll
        for (int r = 0; r < 4; ++r){
          const int bglob = bg*16 + kgrp*4 + r;
          p.out[((size_t)bglob*NS + (size_t)sx)*512 + dir*256 + pcol] = vout[r];
        }
      }
    }
  }
}

extern "C" void kernel_launch(void* const* d_in, const int* in_sizes, int n_in,
                              void* d_out, int out_size, void* d_ws, size_t ws_size,
                              hipStream_t stream) {
  (void)in_sizes; (void)n_in; (void)out_size; (void)ws_size;

  Params prm;
  prm.x     = (const float*)d_in[0];
  prm.Wih_f = (const float*)d_in[1];
  prm.Whh_f = (const float*)d_in[2];
  prm.bih_f = (const float*)d_in[3];
  prm.bhh_f = (const float*)d_in[4];
  prm.Whr_f = (const float*)d_in[5];
  prm.Wih_b = (const float*)d_in[6];
  prm.Whh_b = (const float*)d_in[7];
  prm.bih_b = (const float*)d_in[8];
  prm.bhh_b = (const float*)d_in[9];
  prm.Whr_b = (const float*)d_in[10];
  prm.out   = (float*)d_out;
  prm.ws    = (unsigned char*)d_ws;

  // zero flags + abort + h state (ws re-poisoned 0xAA each launch)
  hipMemsetAsync(d_ws, 0, WS_ZERO, stream);

  // Plain launch: 256 WGs on 256 CUs. >256 VGPRs/wave (weight frags) forces
  // 1 WG/CU, so all WGs are co-resident; abort flag bounds any violation.
  lstm_kernel<<<dim3(TEAMS*TWGS), dim3(NTH), 0, stream>>>(prm);
}

// Round 9
// 10904.150 us; speedup vs baseline: 4.1574x; 4.1574x over previous
//
#include <hip/hip_runtime.h>

// ============================================================================
// Bidirectional LSTM with projection — persistent kernel, rev 5 (resubmit).
//   B=64, S=1024, E=256, H=1024, P=256 ; out (B,S,2*256) fp32
// 8 teams (2 dir x 4 batch-groups of 16), 32 WGs/team, grid 256 x 256 thr.
// rev 5: FENCE-FREE cross-WG sync. All shared data (act, h, flags) moves via
// sc0|sc1 (LLC-direct) loads/stores — the agent coherence point — so no
// buffer_wbl2 / buffer_inv L2 scans (rev 4's 44 us/step cost, per PMC).
// Ordering: s_waitcnt vmcnt(0) before each flag signal; readers' LLC loads
// are issued after the poll load returns. Batched dwordx4 frag loads with
// vmcnt(0)+sched_barrier(0) per the rule-18 hoist hazard.
// Round-7 PMC note: VGPR_Count=256 -> capacity 2 WG/CU; 256-WG co-residency
// guaranteed under any dispatcher placement.
// ============================================================================

#define NS 1024
#define NE 256
#define NH 1024
#define NP 256
#define MB 16
#define NTH 256
#define TEAMS 8
#define TWGS 32

typedef __attribute__((ext_vector_type(8))) short bf16x8;
typedef __attribute__((ext_vector_type(4))) float f32x4;
typedef __attribute__((ext_vector_type(2))) float f32x2;

// ---- ws layout (bytes) ----
// flags: per team 8KB = [act: 32 slots x 128B][h: 32 slots x 128B]
#define WS_FLAGS  0
#define WS_ABORT  65536                    // unsigned abort flag
#define WS_HHI    65792                    // u16 [8][16][256]
#define WS_HLO    (WS_HHI + 65536)
#define WS_ACTHI  (WS_HLO + 65536)         // u16 [8][16][1024]
#define WS_ACTLO  (WS_ACTHI + 262144)
#define WS_END    (WS_ACTLO + 262144)
#define WS_ZERO   WS_ACTHI                 // flags+abort+h must start at 0

#define WAITV0 asm volatile("s_waitcnt vmcnt(0)" ::: "memory")
#define SBAR0  __builtin_amdgcn_sched_barrier(0)

__device__ __forceinline__ unsigned short f2bf_rne(float f){
  unsigned u = __builtin_bit_cast(unsigned, f);
  u += 0x7fffu + ((u >> 16) & 1u);
  return (unsigned short)(u >> 16);
}
__device__ __forceinline__ unsigned short f2bf_tr(float f){
  return (unsigned short)(__builtin_bit_cast(unsigned, f) >> 16);
}
__device__ __forceinline__ float bf2f(unsigned short h){
  unsigned u = ((unsigned)h) << 16;
  return __builtin_bit_cast(float, u);
}
__device__ __forceinline__ f32x4 MFMA(bf16x8 a, bf16x8 b, f32x4 c){
  return __builtin_amdgcn_mfma_f32_16x16x32_bf16(a, b, c, 0, 0, 0);
}
__device__ __forceinline__ float sigmf(float x){ return 1.0f / (1.0f + __expf(-x)); }
__device__ __forceinline__ float tanhfast(float x){
  x = fminf(fmaxf(x, -15.0f), 15.0f);
  float t = __expf(2.0f * x);
  return (t - 1.0f) / (t + 1.0f);
}

// ---- LLC-direct (agent-coherent, no L1/L2 involvement) access helpers ----
__device__ __forceinline__ void st32_llc(unsigned* p, unsigned v){
  asm volatile("global_store_dword %0, %1, off sc0 sc1" :: "v"(p), "v"(v) : "memory");
}
__device__ __forceinline__ void st16_llc(unsigned short* p, unsigned v){
  asm volatile("global_store_short %0, %1, off sc0 sc1" :: "v"(p), "v"(v) : "memory");
}
__device__ __forceinline__ unsigned ld32_llc(const unsigned* p){
  unsigned v;
  asm volatile("global_load_dword %0, %1, off sc0 sc1\n\ts_waitcnt vmcnt(0)"
               : "=v"(v) : "v"(p) : "memory");
  return v;
}
// issue-only 16B LLC load: value NOT ready until a following WAITV0 + SBAR0
__device__ __forceinline__ bf16x8 ldx4_llc(const unsigned short* p){
  bf16x8 v;
  asm volatile("global_load_dwordx4 %0, %1, off sc0 sc1" : "=v"(v) : "v"(p));
  return v;
}

// Wait until all 32 team flags reach tgt. Lane l polls slot (l&31); full-wave
// ballot detects completion. tgt==0 is the s==0 bootstrap (flags memset 0).
__device__ __forceinline__ void wait_flags(const unsigned* flags, unsigned tgt,
                                           unsigned* abortf){
  if (tgt == 0u) return;
  const unsigned* myp = flags + (threadIdx.x & 31) * 32;   // 128B stride
  unsigned it = 0;
  for(;;){
    unsigned v = ld32_llc(myp);
    if (__ballot(v >= tgt) == ~0ULL) break;
    if ((++it & 63u) == 0u){
      if (ld32_llc(abortf) != 0u) return;
      if (it > 200000u){  // bounded: declare deadlock, abort everyone, fail loud
        st32_llc(abortf, 1u);
        return;
      }
    }
  }
}

struct Params {
  const float* x;
  const float* Wih_f; const float* Whh_f; const float* bih_f; const float* bhh_f; const float* Whr_f;
  const float* Wih_b; const float* Whh_b; const float* bih_b; const float* bhh_b; const float* Whr_b;
  float* out;
  unsigned char* ws;
};

__launch_bounds__(NTH, 1)
__global__ void lstm_kernel(Params p){
  // LDS: Gred [4 tilesets][4 gates][16 batch][18] ; G2red [4 waves][16 batch][18]
  __shared__ float Gred[4*4*16*18];    // 18KB
  __shared__ float G2red[4*16*18];     // 4.5KB

  const int tid  = threadIdx.x;
  const int w    = tid >> 6;       // wave 0..3
  const int lane = tid & 63;
  const int rl   = lane & 15;
  const int kgrp = lane >> 4;

  const int bid = blockIdx.x;
  const int tm  = bid & 7;         // team
  const int wg  = bid >> 3;        // 0..31 within team
  const int dir = tm >> 2;
  const int bg  = tm & 3;

  const float* Wih = dir ? p.Wih_b : p.Wih_f;
  const float* Whh = dir ? p.Whh_b : p.Whh_f;
  const float* bih = dir ? p.bih_b : p.bih_f;
  const float* bhh = dir ? p.bhh_b : p.bhh_f;
  const float* Whr = dir ? p.Whr_b : p.Whr_f;

  unsigned* act_flags = (unsigned*)(p.ws + WS_FLAGS + tm*8192);
  unsigned* h_flags   = (unsigned*)(p.ws + WS_FLAGS + tm*8192 + 4096);
  unsigned* my_act_flag = act_flags + wg*32;   // this WG's 128B slot
  unsigned* my_h_flag   = h_flags   + wg*32;
  unsigned* abortf  = (unsigned*)(p.ws + WS_ABORT);
  unsigned short* h_hi   = (unsigned short*)(p.ws + WS_HHI)   + tm*MB*NP;
  unsigned short* h_lo   = (unsigned short*)(p.ws + WS_HLO)   + tm*MB*NP;
  unsigned short* act_hi = (unsigned short*)(p.ws + WS_ACTHI) + tm*MB*NH;
  unsigned short* act_lo = (unsigned short*)(p.ws + WS_ACTLO) + tm*MB*NH;

  // Roles: hb = which 16 of this WG's 32 h-indices; kh = K-half
  //   kh==0 -> A = h(s-1) (W_hh), kh==1 -> A = x[sx] (W_ih)
  const int hb = w & 1;
  const int kh = w >> 1;

  // -------- W1 slice (hi+lo) -> VGPR B-frags: whi/wlo[gate][ktile] ----------
  const float* Wsel = kh ? Wih : Whh;
  bf16x8 whi[4][8], wlo[4][8];
  #pragma unroll
  for (int g = 0; g < 4; ++g){
    const float* Wrow = Wsel + (size_t)(g*NH + wg*32 + hb*16 + rl)*NE;
    #pragma unroll
    for (int kt = 0; kt < 8; ++kt){
      const int k0 = kt*32 + kgrp*8;
      #pragma unroll
      for (int j = 0; j < 8; ++j){
        float v = Wrow[k0 + j];
        unsigned short hv = f2bf_rne(v);
        whi[g][kt][j] = (short)hv;
        wlo[g][kt][j] = (short)f2bf_rne(v - bf2f(hv));
      }
    }
  }

  // -------- W_hr slice (hi+lo) -> VGPR B-frags; wave w owns K chunk --------
  bf16x8 whrh[8], whrl[8];
  #pragma unroll
  for (int q = 0; q < 8; ++q){
    const int k0 = w*256 + q*32 + kgrp*8;
    #pragma unroll
    for (int j = 0; j < 8; ++j){
      float v = (rl < 8) ? Whr[(size_t)(wg*8 + rl)*NH + k0 + j] : 0.0f;
      unsigned short hv = f2bf_rne(v);
      whrh[q][j] = (short)hv;
      whrl[q][j] = (short)f2bf_rne(v - bf2f(hv));
    }
  }

  // -------- bias (added once, kh==0 half only) -----------------------------
  float bias[4];
  #pragma unroll
  for (int g = 0; g < 4; ++g){
    const int grow = g*NH + wg*32 + hb*16 + rl;
    bias[g] = (kh == 0) ? (bih[grow] + bhh[grow]) : 0.0f;
  }

  // -------- gate-phase role: thread owns (hb, batch gb16, h-pair ghidx) ----
  const int bh2   = w >> 1;
  const int idx0  = lane * 2;
  const int gb16  = bh2*8 + (idx0 >> 4);
  const int ghidx = idx0 & 15;
  float c0 = 0.0f, c1 = 0.0f;          // persistent cell state (fp32)

  for (int s = 0; s < NS; ++s){
    const int sx = dir ? (NS-1-s) : s;

    f32x4 acc[4];
    #pragma unroll
    for (int g = 0; g < 4; ++g) acc[g] = (f32x4){bias[g], bias[g], bias[g], bias[g]};

    if (kh == 0){
      // recurrent half: wait for h(s-1) (s==0 passes: flags zeroed)
      wait_flags(h_flags, (unsigned)s, abortf);
      #pragma unroll
      for (int gk = 0; gk < 2; ++gk){
        bf16x8 ah[4], al[4];
        #pragma unroll
        for (int kt2 = 0; kt2 < 4; ++kt2){
          const int k0 = (gk*4 + kt2)*32 + kgrp*8;
          ah[kt2] = ldx4_llc(h_hi + rl*NP + k0);
          al[kt2] = ldx4_llc(h_lo + rl*NP + k0);
        }
        WAITV0; SBAR0;
        #pragma unroll
        for (int kt2 = 0; kt2 < 4; ++kt2){
          const int kt = gk*4 + kt2;
          #pragma unroll
          for (int g = 0; g < 4; ++g){
            acc[g] = MFMA(ah[kt2], whi[g][kt], acc[g]);
            acc[g] = MFMA(al[kt2], whi[g][kt], acc[g]);
            acc[g] = MFMA(ah[kt2], wlo[g][kt], acc[g]);
          }
        }
      }
    } else {
      // input half: no dependence on previous step; x is read-only (normal loads)
      const float* xb = p.x + ((size_t)(bg*16 + rl)*NS + (size_t)sx)*NE;
      #pragma unroll
      for (int kt = 0; kt < 8; ++kt){
        const int k0 = kt*32 + kgrp*8;
        f32x4 va = *(const f32x4*)(xb + k0);
        f32x4 vb = *(const f32x4*)(xb + k0 + 4);
        bf16x8 ahi, alo;
        #pragma unroll
        for (int j = 0; j < 4; ++j){
          unsigned short h1 = f2bf_tr(va[j]);
          ahi[j]   = (short)h1; alo[j]   = (short)f2bf_tr(va[j] - bf2f(h1));
          unsigned short h2 = f2bf_tr(vb[j]);
          ahi[j+4] = (short)h2; alo[j+4] = (short)f2bf_tr(vb[j] - bf2f(h2));
        }
        #pragma unroll
        for (int g = 0; g < 4; ++g){
          acc[g] = MFMA(ahi, whi[g][kt], acc[g]);
          acc[g] = MFMA(alo, whi[g][kt], acc[g]);
          acc[g] = MFMA(ahi, wlo[g][kt], acc[g]);
        }
      }
    }

    // deposit partials: D lane layout row(batch)=kgrp*4+r, col(h)=rl
    #pragma unroll
    for (int g = 0; g < 4; ++g){
      #pragma unroll
      for (int r = 0; r < 4; ++r)
        Gred[(((kh*2+hb)*4 + g)*16 + (kgrp*4 + r))*18 + rl] = acc[g][r];
    }
    __syncthreads();

    // ---- gates + cell update + activation (2 h-elems per thread) ----------
    {
      unsigned short ahi16[2], alo16[2];
      float gs[4][2];
      #pragma unroll
      for (int g = 0; g < 4; ++g){
        f32x2 a0 = *(const f32x2*)&Gred[((hb*4 + g)*16 + gb16)*18 + ghidx];
        f32x2 a1 = *(const f32x2*)&Gred[(((2+hb)*4 + g)*16 + gb16)*18 + ghidx];
        gs[g][0] = a0[0] + a1[0];
        gs[g][1] = a0[1] + a1[1];
      }
      #pragma unroll
      for (int j = 0; j < 2; ++j){
        float iv = sigmf(gs[0][j]);
        float fv = sigmf(gs[1][j]);
        float gv = tanhfast(gs[2][j]);
        float ov = sigmf(gs[3][j]);
        float c  = fv * (j ? c1 : c0) + iv * gv;
        if (j) c1 = c; else c0 = c;
        float a  = ov * tanhfast(c);
        ahi16[j] = f2bf_tr(a);
        alo16[j] = f2bf_tr(a - bf2f(ahi16[j]));
      }
      const unsigned colg = (unsigned)(wg*32 + hb*16 + ghidx);
      st32_llc((unsigned*)(act_hi + gb16*NH + colg),
               (unsigned)ahi16[0] | ((unsigned)ahi16[1] << 16));
      st32_llc((unsigned*)(act_lo + gb16*NH + colg),
               (unsigned)alo16[0] | ((unsigned)alo16[1] << 16));
    }
    WAITV0;                 // my act stores ack'd at LLC
    __syncthreads();        // all threads' stores ack'd
    if (tid == 0)
      st32_llc(my_act_flag, (unsigned)(s+1));
    wait_flags(act_flags, (unsigned)(s+1), abortf);

    // ---- GEMM2: h = act @ W_hr.T ; waves split K=1024, LDS reduce ---------
    f32x4 acc2 = (f32x4){0.0f, 0.0f, 0.0f, 0.0f};
    #pragma unroll
    for (int gq = 0; gq < 2; ++gq){
      bf16x8 ah[4], al[4];
      #pragma unroll
      for (int q2 = 0; q2 < 4; ++q2){
        const int k0 = w*256 + (gq*4 + q2)*32 + kgrp*8;
        ah[q2] = ldx4_llc(act_hi + rl*NH + k0);
        al[q2] = ldx4_llc(act_lo + rl*NH + k0);
      }
      WAITV0; SBAR0;
      #pragma unroll
      for (int q2 = 0; q2 < 4; ++q2){
        const int q = gq*4 + q2;
        acc2 = MFMA(ah[q2], whrh[q], acc2);
        acc2 = MFMA(al[q2], whrh[q], acc2);
        acc2 = MFMA(ah[q2], whrl[q], acc2);
      }
    }
    #pragma unroll
    for (int r = 0; r < 4; ++r)
      G2red[(w*16 + (kgrp*4 + r))*18 + rl] = acc2[r];
    __syncthreads();

    // ---- projection reduce: h-write + signal FIRST, out-store AFTER -------
    float vout[4];
    if (w == 0){
      #pragma unroll
      for (int r = 0; r < 4; ++r){
        const int b16 = kgrp*4 + r;
        float v = G2red[(0*16 + b16)*18 + rl] + G2red[(1*16 + b16)*18 + rl]
                + G2red[(2*16 + b16)*18 + rl] + G2red[(3*16 + b16)*18 + rl];
        vout[r] = v;
        if (rl < 8){
          const int pcol = wg*8 + rl;
          unsigned short hh = f2bf_tr(v);
          st16_llc(h_hi + b16*NP + pcol, (unsigned)hh);
          st16_llc(h_lo + b16*NP + pcol, (unsigned)f2bf_tr(v - bf2f(hh)));
        }
      }
      WAITV0;               // wave-level: all wave-0 lanes' h stores ack'd at LLC
      if (lane == 0)
        st32_llc(my_h_flag, (unsigned)(s+1));

      if (rl < 8){
        // write-only output; retires during the next step's spin window
        const int pcol = wg*8 + rl;
        #pragma unroll
        for (int r = 0; r < 4; ++r){
          const int bglob = bg*16 + kgrp*4 + r;
          p.out[((size_t)bglob*NS + (size_t)sx)*512 + dir*256 + pcol] = vout[r];
        }
      }
    }
  }
}

extern "C" void kernel_launch(void* const* d_in, const int* in_sizes, int n_in,
                              void* d_out, int out_size, void* d_ws, size_t ws_size,
                              hipStream_t stream) {
  (void)in_sizes; (void)n_in; (void)out_size; (void)ws_size;

  Params prm;
  prm.x     = (const float*)d_in[0];
  prm.Wih_f = (const float*)d_in[1];
  prm.Whh_f = (const float*)d_in[2];
  prm.bih_f = (const float*)d_in[3];
  prm.bhh_f = (const float*)d_in[4];
  prm.Whr_f = (const float*)d_in[5];
  prm.Wih_b = (const float*)d_in[6];
  prm.Whh_b = (const float*)d_in[7];
  prm.bih_b = (const float*)d_in[8];
  prm.bhh_b = (const float*)d_in[9];
  prm.Whr_b = (const float*)d_in[10];
  prm.out   = (float*)d_out;
  prm.ws    = (unsigned char*)d_ws;

  // zero flags + abort + h state (ws re-poisoned 0xAA each launch)
  hipMemsetAsync(d_ws, 0, WS_ZERO, stream);

  // Plain launch: 256 WGs on 256 CUs; 256 VGPRs/wave -> capacity 2 WG/CU,
  // so all 256 WGs are co-resident under any placement; abort flag bounds
  // any violation.
  lstm_kernel<<<dim3(TEAMS*TWGS), dim3(NTH), 0, stream>>>(prm);
}

// Round 10
// 9107.668 us; speedup vs baseline: 4.9774x; 1.1972x over previous
//
#include <hip/hip_runtime.h>

// ============================================================================
// Bidirectional LSTM with projection — persistent kernel, rev 6.
//   B=64, S=1024, E=256, H=1024, P=256 ; out (B,S,2*256) fp32
// 8 teams (2 dir x 4 batch-groups of 16), 32 WGs/team, grid 256 x 256 thr.
// rev 5: LLC-direct (sc0 sc1) cross-WG data+flags, no agent fences. 45.3->10.9ms.
// rev 6: cut the LLC latency chain:
//   (1) k-blocked layouts [k/8][batch][8k] for h/act -> frag loads are one
//       contiguous 1KB per wave instruction (was 16-way 64B gather);
//   (2) single 16-load batch per GEMM (one vmcnt(0) each, -2 RT/step);
//   (3) per-wave act wait: wave w polls only its 8 producer WGs (8w..8w+7)
//       instead of all 32 (no team-wide straggler convoy).
// Abort flag bounds any spin (~15ms) -> fails loud, never hangs.
// ============================================================================

#define NS 1024
#define NE 256
#define NH 1024
#define NP 256
#define MB 16
#define NTH 256
#define TEAMS 8
#define TWGS 32

typedef __attribute__((ext_vector_type(8))) short bf16x8;
typedef __attribute__((ext_vector_type(4))) float f32x4;
typedef __attribute__((ext_vector_type(2))) float f32x2;

// ---- ws layout (bytes) ----
// flags: per team 8KB = [act: 32 slots x 128B][h: 32 slots x 128B]
#define WS_FLAGS  0
#define WS_ABORT  65536                    // unsigned abort flag
#define WS_HHI    65792                    // per team 8KB:  [32 kblk][16 b][8k bf16]
#define WS_HLO    (WS_HHI + 65536)
#define WS_ACTHI  (WS_HLO + 65536)         // per team 32KB: [128 kblk][16 b][8k bf16]
#define WS_ACTLO  (WS_ACTHI + 262144)
#define WS_END    (WS_ACTLO + 262144)
#define WS_ZERO   WS_ACTHI                 // flags+abort+h planes must start at 0

#define WAITV0 asm volatile("s_waitcnt vmcnt(0)" ::: "memory")
#define SBAR0  __builtin_amdgcn_sched_barrier(0)

__device__ __forceinline__ unsigned short f2bf_rne(float f){
  unsigned u = __builtin_bit_cast(unsigned, f);
  u += 0x7fffu + ((u >> 16) & 1u);
  return (unsigned short)(u >> 16);
}
__device__ __forceinline__ unsigned short f2bf_tr(float f){
  return (unsigned short)(__builtin_bit_cast(unsigned, f) >> 16);
}
__device__ __forceinline__ float bf2f(unsigned short h){
  unsigned u = ((unsigned)h) << 16;
  return __builtin_bit_cast(float, u);
}
__device__ __forceinline__ f32x4 MFMA(bf16x8 a, bf16x8 b, f32x4 c){
  return __builtin_amdgcn_mfma_f32_16x16x32_bf16(a, b, c, 0, 0, 0);
}
__device__ __forceinline__ float sigmf(float x){ return 1.0f / (1.0f + __expf(-x)); }
__device__ __forceinline__ float tanhfast(float x){
  x = fminf(fmaxf(x, -15.0f), 15.0f);
  float t = __expf(2.0f * x);
  return (t - 1.0f) / (t + 1.0f);
}

// ---- LLC-direct (agent-coherent) access helpers ----
__device__ __forceinline__ void st32_llc(void* p, unsigned v){
  asm volatile("global_store_dword %0, %1, off sc0 sc1" :: "v"(p), "v"(v) : "memory");
}
__device__ __forceinline__ void st16_llc(void* p, unsigned v){
  asm volatile("global_store_short %0, %1, off sc0 sc1" :: "v"(p), "v"(v) : "memory");
}
__device__ __forceinline__ unsigned ld32_llc(const void* p){
  unsigned v;
  asm volatile("global_load_dword %0, %1, off sc0 sc1\n\ts_waitcnt vmcnt(0)"
               : "=v"(v) : "v"(p) : "memory");
  return v;
}
// issue-only 16B LLC load: value NOT ready until a following WAITV0 + SBAR0
__device__ __forceinline__ bf16x8 ldx4_llc(const void* p){
  bf16x8 v;
  asm volatile("global_load_dwordx4 %0, %1, off sc0 sc1" : "=v"(v) : "v"(p));
  return v;
}

// Wait until all 32 team flags reach tgt (lane l polls slot l&31).
__device__ __forceinline__ void wait_flags32(const unsigned* flags, unsigned tgt,
                                             unsigned* abortf){
  if (tgt == 0u) return;
  const unsigned* myp = flags + (threadIdx.x & 31) * 32;   // 128B stride
  unsigned it = 0;
  for(;;){
    unsigned v = ld32_llc(myp);
    if (__ballot(v >= tgt) == ~0ULL) break;
    if ((++it & 63u) == 0u){
      if (ld32_llc(abortf) != 0u) return;
      if (it > 200000u){ st32_llc(abortf, 1u); return; }
    }
  }
}
// Wait until 8 producer flags (base..base+7 slots) reach tgt (lane l&7).
__device__ __forceinline__ void wait_flags8(const unsigned* base8, unsigned tgt,
                                            unsigned* abortf){
  if (tgt == 0u) return;
  const unsigned* myp = base8 + (threadIdx.x & 7) * 32;
  unsigned it = 0;
  for(;;){
    unsigned v = ld32_llc(myp);
    if (__ballot(v >= tgt) == ~0ULL) break;
    if ((++it & 63u) == 0u){
      if (ld32_llc(abortf) != 0u) return;
      if (it > 200000u){ st32_llc(abortf, 1u); return; }
    }
  }
}

struct Params {
  const float* x;
  const float* Wih_f; const float* Whh_f; const float* bih_f; const float* bhh_f; const float* Whr_f;
  const float* Wih_b; const float* Whh_b; const float* bih_b; const float* bhh_b; const float* Whr_b;
  float* out;
  unsigned char* ws;
};

__launch_bounds__(NTH, 1)
__global__ void lstm_kernel(Params p){
  // LDS: Gred [4 tilesets][4 gates][16 batch][18] ; G2red [4 waves][16 batch][18]
  __shared__ float Gred[4*4*16*18];    // 18KB
  __shared__ float G2red[4*16*18];     // 4.5KB

  const int tid  = threadIdx.x;
  const int w    = tid >> 6;       // wave 0..3
  const int lane = tid & 63;
  const int rl   = lane & 15;
  const int kgrp = lane >> 4;

  const int bid = blockIdx.x;
  const int tm  = bid & 7;         // team (XCD-affine heuristic; perf-only)
  const int wg  = bid >> 3;        // 0..31 within team
  const int dir = tm >> 2;
  const int bg  = tm & 3;

  const float* Wih = dir ? p.Wih_b : p.Wih_f;
  const float* Whh = dir ? p.Whh_b : p.Whh_f;
  const float* bih = dir ? p.bih_b : p.bih_f;
  const float* bhh = dir ? p.bhh_b : p.bhh_f;
  const float* Whr = dir ? p.Whr_b : p.Whr_f;

  unsigned* act_flags = (unsigned*)(p.ws + WS_FLAGS + tm*8192);
  unsigned* h_flags   = (unsigned*)(p.ws + WS_FLAGS + tm*8192 + 4096);
  unsigned* my_act_flag = act_flags + wg*32;   // this WG's 128B slot
  unsigned* my_h_flag   = h_flags   + wg*32;
  unsigned* abortf  = (unsigned*)(p.ws + WS_ABORT);
  // k-blocked planes: cell (kblk,b) at byte kblk*256 + b*16; elem k at +(k&7)*2
  unsigned char* h_hi   = p.ws + WS_HHI   + tm*8192;
  unsigned char* h_lo   = p.ws + WS_HLO   + tm*8192;
  unsigned char* act_hi = p.ws + WS_ACTHI + tm*32768;
  unsigned char* act_lo = p.ws + WS_ACTLO + tm*32768;

  // Roles: hb = which 16 of this WG's 32 h-indices; kh = K-half
  //   kh==0 -> A = h(s-1) (W_hh), kh==1 -> A = x[sx] (W_ih)
  const int hb = w & 1;
  const int kh = w >> 1;

  // -------- W1 slice (hi+lo) -> VGPR B-frags: whi/wlo[gate][ktile] ----------
  const float* Wsel = kh ? Wih : Whh;
  bf16x8 whi[4][8], wlo[4][8];
  #pragma unroll
  for (int g = 0; g < 4; ++g){
    const float* Wrow = Wsel + (size_t)(g*NH + wg*32 + hb*16 + rl)*NE;
    #pragma unroll
    for (int kt = 0; kt < 8; ++kt){
      const int k0 = kt*32 + kgrp*8;
      #pragma unroll
      for (int j = 0; j < 8; ++j){
        float v = Wrow[k0 + j];
        unsigned short hv = f2bf_rne(v);
        whi[g][kt][j] = (short)hv;
        wlo[g][kt][j] = (short)f2bf_rne(v - bf2f(hv));
      }
    }
  }

  // -------- W_hr slice (hi+lo) -> VGPR B-frags; wave w owns K chunk --------
  bf16x8 whrh[8], whrl[8];
  #pragma unroll
  for (int q = 0; q < 8; ++q){
    const int k0 = w*256 + q*32 + kgrp*8;
    #pragma unroll
    for (int j = 0; j < 8; ++j){
      float v = (rl < 8) ? Whr[(size_t)(wg*8 + rl)*NH + k0 + j] : 0.0f;
      unsigned short hv = f2bf_rne(v);
      whrh[q][j] = (short)hv;
      whrl[q][j] = (short)f2bf_rne(v - bf2f(hv));
    }
  }

  // -------- bias (added once, kh==0 half only) -----------------------------
  float bias[4];
  #pragma unroll
  for (int g = 0; g < 4; ++g){
    const int grow = g*NH + wg*32 + hb*16 + rl;
    bias[g] = (kh == 0) ? (bih[grow] + bhh[grow]) : 0.0f;
  }

  // -------- gate-phase role: thread owns (hb, batch gb16, h-pair ghidx) ----
  const int bh2   = w >> 1;
  const int idx0  = lane * 2;
  const int gb16  = bh2*8 + (idx0 >> 4);
  const int ghidx = idx0 & 15;
  float c0 = 0.0f, c1 = 0.0f;          // persistent cell state (fp32)

  // frag-load byte offset within a 1KB k-block row: contiguous across the wave
  const int fo = kgrp*256 + rl*16;

  for (int s = 0; s < NS; ++s){
    const int sx = dir ? (NS-1-s) : s;

    f32x4 acc[4];
    #pragma unroll
    for (int g = 0; g < 4; ++g) acc[g] = (f32x4){bias[g], bias[g], bias[g], bias[g]};

    if (kh == 0){
      // recurrent half: wait for h(s-1) (s==0 passes: flags zeroed)
      wait_flags32(h_flags, (unsigned)s, abortf);
      bf16x8 ah[8], al[8];
      #pragma unroll
      for (int kt = 0; kt < 8; ++kt){
        ah[kt] = ldx4_llc(h_hi + kt*1024 + fo);
        al[kt] = ldx4_llc(h_lo + kt*1024 + fo);
      }
      WAITV0; SBAR0;
      #pragma unroll
      for (int kt = 0; kt < 8; ++kt){
        #pragma unroll
        for (int g = 0; g < 4; ++g){
          acc[g] = MFMA(ah[kt], whi[g][kt], acc[g]);
          acc[g] = MFMA(al[kt], whi[g][kt], acc[g]);
          acc[g] = MFMA(ah[kt], wlo[g][kt], acc[g]);
        }
      }
    } else {
      // input half: no dependence on previous step; x is read-only (normal loads)
      const float* xb = p.x + ((size_t)(bg*16 + rl)*NS + (size_t)sx)*NE;
      #pragma unroll
      for (int kt = 0; kt < 8; ++kt){
        const int k0 = kt*32 + kgrp*8;
        f32x4 va = *(const f32x4*)(xb + k0);
        f32x4 vb = *(const f32x4*)(xb + k0 + 4);
        bf16x8 ahi, alo;
        #pragma unroll
        for (int j = 0; j < 4; ++j){
          unsigned short h1 = f2bf_tr(va[j]);
          ahi[j]   = (short)h1; alo[j]   = (short)f2bf_tr(va[j] - bf2f(h1));
          unsigned short h2 = f2bf_tr(vb[j]);
          ahi[j+4] = (short)h2; alo[j+4] = (short)f2bf_tr(vb[j] - bf2f(h2));
        }
        #pragma unroll
        for (int g = 0; g < 4; ++g){
          acc[g] = MFMA(ahi, whi[g][kt], acc[g]);
          acc[g] = MFMA(alo, whi[g][kt], acc[g]);
          acc[g] = MFMA(ahi, wlo[g][kt], acc[g]);
        }
      }
    }

    // deposit partials: D lane layout row(batch)=kgrp*4+r, col(h)=rl
    #pragma unroll
    for (int g = 0; g < 4; ++g){
      #pragma unroll
      for (int r = 0; r < 4; ++r)
        Gred[(((kh*2+hb)*4 + g)*16 + (kgrp*4 + r))*18 + rl] = acc[g][r];
    }
    __syncthreads();

    // ---- gates + cell update + activation (2 h-elems per thread) ----------
    {
      unsigned short ahi16[2], alo16[2];
      float gs[4][2];
      #pragma unroll
      for (int g = 0; g < 4; ++g){
        f32x2 a0 = *(const f32x2*)&Gred[((hb*4 + g)*16 + gb16)*18 + ghidx];
        f32x2 a1 = *(const f32x2*)&Gred[(((2+hb)*4 + g)*16 + gb16)*18 + ghidx];
        gs[g][0] = a0[0] + a1[0];
        gs[g][1] = a0[1] + a1[1];
      }
      #pragma unroll
      for (int j = 0; j < 2; ++j){
        float iv = sigmf(gs[0][j]);
        float fv = sigmf(gs[1][j]);
        float gv = tanhfast(gs[2][j]);
        float ov = sigmf(gs[3][j]);
        float c  = fv * (j ? c1 : c0) + iv * gv;
        if (j) c1 = c; else c0 = c;
        float a  = ov * tanhfast(c);
        ahi16[j] = f2bf_tr(a);
        alo16[j] = f2bf_tr(a - bf2f(ahi16[j]));
      }
      // k-blocked store: both elems in one aligned dword
      const unsigned colg  = (unsigned)(wg*32 + hb*16 + ghidx);
      const unsigned abyte = (colg >> 3)*256 + (unsigned)gb16*16 + (colg & 7)*2;
      st32_llc(act_hi + abyte, (unsigned)ahi16[0] | ((unsigned)ahi16[1] << 16));
      st32_llc(act_lo + abyte, (unsigned)alo16[0] | ((unsigned)alo16[1] << 16));
    }
    WAITV0;                 // my act stores ack'd at LLC
    __syncthreads();        // all threads' stores ack'd
    if (tid == 0)
      st32_llc(my_act_flag, (unsigned)(s+1));
    // per-wave wait: only the 8 WGs producing this wave's K-chunk
    wait_flags8(act_flags + w*256, (unsigned)(s+1), abortf);

    // ---- GEMM2: h = act @ W_hr.T ; waves split K=1024, LDS reduce ---------
    f32x4 acc2 = (f32x4){0.0f, 0.0f, 0.0f, 0.0f};
    {
      bf16x8 bh[8], bl[8];
      #pragma unroll
      for (int q = 0; q < 8; ++q){
        bh[q] = ldx4_llc(act_hi + w*8192 + q*1024 + fo);
        bl[q] = ldx4_llc(act_lo + w*8192 + q*1024 + fo);
      }
      WAITV0; SBAR0;
      #pragma unroll
      for (int q = 0; q < 8; ++q){
        acc2 = MFMA(bh[q], whrh[q], acc2);
        acc2 = MFMA(bl[q], whrh[q], acc2);
        acc2 = MFMA(bh[q], whrl[q], acc2);
      }
    }
    #pragma unroll
    for (int r = 0; r < 4; ++r)
      G2red[(w*16 + (kgrp*4 + r))*18 + rl] = acc2[r];
    __syncthreads();

    // ---- projection reduce: h-write + signal FIRST, out-store AFTER -------
    float vout[4];
    if (w == 0){
      #pragma unroll
      for (int r = 0; r < 4; ++r){
        const int b16 = kgrp*4 + r;
        float v = G2red[(0*16 + b16)*18 + rl] + G2red[(1*16 + b16)*18 + rl]
                + G2red[(2*16 + b16)*18 + rl] + G2red[(3*16 + b16)*18 + rl];
        vout[r] = v;
        if (rl < 8){
          // pcol = wg*8+rl -> kblk = wg, elem rl: byte = wg*256 + b16*16 + rl*2
          unsigned short hh = f2bf_tr(v);
          st16_llc(h_hi + wg*256 + b16*16 + rl*2, (unsigned)hh);
          st16_llc(h_lo + wg*256 + b16*16 + rl*2, (unsigned)f2bf_tr(v - bf2f(hh)));
        }
      }
      WAITV0;               // wave-level: all wave-0 lanes' h stores ack'd at LLC
      if (lane == 0)
        st32_llc(my_h_flag, (unsigned)(s+1));

      if (rl < 8){
        // write-only output; retires during the next step's spin window
        const int pcol = wg*8 + rl;
        #pragma unroll
        for (int r = 0; r < 4; ++r){
          const int bglob = bg*16 + kgrp*4 + r;
          p.out[((size_t)bglob*NS + (size_t)sx)*512 + dir*256 + pcol] = vout[r];
        }
      }
    }
  }
}

extern "C" void kernel_launch(void* const* d_in, const int* in_sizes, int n_in,
                              void* d_out, int out_size, void* d_ws, size_t ws_size,
                              hipStream_t stream) {
  (void)in_sizes; (void)n_in; (void)out_size; (void)ws_size;

  Params prm;
  prm.x     = (const float*)d_in[0];
  prm.Wih_f = (const float*)d_in[1];
  prm.Whh_f = (const float*)d_in[2];
  prm.bih_f = (const float*)d_in[3];
  prm.bhh_f = (const float*)d_in[4];
  prm.Whr_f = (const float*)d_in[5];
  prm.Wih_b = (const float*)d_in[6];
  prm.Whh_b = (const float*)d_in[7];
  prm.bih_b = (const float*)d_in[8];
  prm.bhh_b = (const float*)d_in[9];
  prm.Whr_b = (const float*)d_in[10];
  prm.out   = (float*)d_out;
  prm.ws    = (unsigned char*)d_ws;

  // zero flags + abort + h planes (ws re-poisoned 0xAA each launch)
  hipMemsetAsync(d_ws, 0, WS_ZERO, stream);

  // Plain launch: 256 WGs on 256 CUs; 256 VGPRs/wave -> capacity 2 WG/CU,
  // so all 256 WGs are co-resident under any placement; abort flag bounds
  // any violation.
  lstm_kernel<<<dim3(TEAMS*TWGS), dim3(NTH), 0, stream>>>(prm);
}